// Round 1
// baseline (358.983 us; speedup 1.0000x reference)
//
#include <hip/hip_runtime.h>

#define NSTEP 365
#define NGRID 50000
#define HALF  25000
#define PRECS_F 1e-5f
#define CHUNK 8

#if defined(__has_builtin)
#  if __has_builtin(__builtin_amdgcn_exp2f) && __has_builtin(__builtin_amdgcn_logf)
#    define FAST_EXP2(x) __builtin_amdgcn_exp2f(x)
#    define FAST_LOG2(x) __builtin_amdgcn_logf(x)
#  endif
#endif
#ifndef FAST_EXP2
#  define FAST_EXP2(x) exp2f(x)
#  define FAST_LOG2(x) log2f(x)
#endif

// 2 independent grid cells per thread: the per-step state update is a serial
// dependency chain (~30 dependent VALU ops incl. log2->mul->exp2); with only
// 782 waves on 1024 SIMDs there is no TLP to hide its latency. Interleaving
// two independent chains per lane fills the pipeline bubbles (ILP=2).
__global__ __launch_bounds__(64) void hbv_kernel(const float* __restrict__ x,
                                                 const float* __restrict__ params,
                                                 float* __restrict__ out) {
    const int g0 = blockIdx.x * blockDim.x + threadIdx.x;
    if (g0 >= HALF) return;
    const int gi[2] = {g0, g0 + HALF};   // both streams stay lane-coalesced

    // ---- scale parameters for both cells: p = lo + raw * (hi - lo) ----
    float parBETA[2], parK0[2], parK1[2], parK2[2], parPERC[2], parUZL[2];
    float parTT[2], parCFMAX[2], parCWH[2], parFC[2];
    float invFC[2], invLPFC[2], cfr_cfmax[2];

    #pragma unroll
    for (int c = 0; c < 2; ++c) {
        const float* pr = params + (size_t)gi[c] * 14;
        const float r0 = pr[0], r1 = pr[1], r2 = pr[2], r3 = pr[3], r4 = pr[4], r5 = pr[5];
        const float r6 = pr[6], r7 = pr[7], r8 = pr[8], r9 = pr[9], r10 = pr[10], r11 = pr[11];

        parBETA[c]  = 1.0f   + r0  * 5.0f;
        parFC[c]    = 50.0f  + r1  * 950.0f;
        parK0[c]    = 0.05f  + r2  * 0.85f;
        parK1[c]    = 0.01f  + r3  * 0.49f;
        parK2[c]    = 0.001f + r4  * 0.199f;
        const float parLP = 0.2f + r5 * 0.8f;
        parPERC[c]  =          r6  * 10.0f;
        parUZL[c]   =          r7  * 100.0f;
        parTT[c]    = -2.5f  + r8  * 5.0f;
        parCFMAX[c] = 0.5f   + r9  * 9.5f;
        const float parCFR = r10 * 0.1f;
        parCWH[c]   =          r11 * 0.2f;

        invFC[c]     = 1.0f / parFC[c];
        invLPFC[c]   = 1.0f / (parLP * parFC[c]);
        cfr_cfmax[c] = parCFR * parCFMAX[c];
    }

    float SNOWPACK[2]  = {0.001f, 0.001f};
    float MELTWATER[2] = {0.001f, 0.001f};
    float SM[2]        = {0.001f, 0.001f};
    float SUZ[2]       = {0.001f, 0.001f};
    float SLZ[2]       = {0.001f, 0.001f};

    const int nchunks = (NSTEP + CHUNK - 1) / CHUNK;  // 46 (even -> both pipeline bufs used)

    float AP[2][CHUNK], AT[2][CHUNK], AE[2][CHUNK];
    float BP[2][CHUNK], BT[2][CHUNK], BE[2][CHUNK];

    auto load_chunk = [&](int cidx, float (&P)[2][CHUNK], float (&T)[2][CHUNK],
                          float (&E)[2][CHUNK]) {
        const int tbase = cidx * CHUNK;
        #pragma unroll
        for (int j = 0; j < CHUNK; ++j) {
            int t = tbase + j;
            t = (t < NSTEP) ? t : (NSTEP - 1);            // clamp (tail chunk)
            const float* p0 = x + ((size_t)t * NGRID + gi[0]) * 3;
            const float* p1 = x + ((size_t)t * NGRID + gi[1]) * 3;
            P[0][j] = p0[0]; T[0][j] = p0[1]; E[0][j] = p0[2];
            P[1][j] = p1[0]; T[1][j] = p1[1]; E[1][j] = p1[2];
        }
    };

    auto compute_chunk = [&](int cidx, const float (&P)[2][CHUNK], const float (&T)[2][CHUNK],
                             const float (&E)[2][CHUNK]) {
        const int t0 = cidx * CHUNK;
        #pragma unroll
        for (int j = 0; j < CHUNK; ++j) {
            float q[2];
            #pragma unroll
            for (int c = 0; c < 2; ++c) {     // two independent chains -> ILP
                const float PRECIP = P[c][j];
                const float Tt     = T[c][j];
                const float ETp    = E[c][j];

                float RAIN = (Tt >= parTT[c]) ? PRECIP : 0.0f;
                float SNOW = PRECIP - RAIN;
                SNOWPACK[c] += SNOW;
                float melt = fminf(fmaxf(parCFMAX[c] * (Tt - parTT[c]), 0.0f), SNOWPACK[c]);
                MELTWATER[c] += melt;
                SNOWPACK[c]  -= melt;
                float refreeze = fminf(fmaxf(cfr_cfmax[c] * (parTT[c] - Tt), 0.0f), MELTWATER[c]);
                SNOWPACK[c]  += refreeze;
                MELTWATER[c] -= refreeze;
                float tosoil = fmaxf(MELTWATER[c] - parCWH[c] * SNOWPACK[c], 0.0f);
                MELTWATER[c] -= tosoil;

                float ratio = SM[c] * invFC[c];           // SM in (0, FC] -> ratio in (0, 1]
                float sw = FAST_EXP2(parBETA[c] * FAST_LOG2(ratio));
                sw = fminf(fmaxf(sw, 0.0f), 1.0f);
                float recharge = (RAIN + tosoil) * sw;
                SM[c] += RAIN + tosoil - recharge;
                float excess = fmaxf(SM[c] - parFC[c], 0.0f);
                SM[c] -= excess;
                float evapfactor = fminf(fmaxf(SM[c] * invLPFC[c], 0.0f), 1.0f);
                float ETact = fminf(SM[c], ETp * evapfactor);
                SM[c] = fmaxf(SM[c] - ETact, PRECS_F);

                SUZ[c] += recharge + excess;
                float PERC = fminf(SUZ[c], parPERC[c]);
                SUZ[c] -= PERC;
                float Q0 = parK0[c] * fmaxf(SUZ[c] - parUZL[c], 0.0f);
                SUZ[c] -= Q0;
                float Q1 = parK1[c] * SUZ[c];
                SUZ[c] -= Q1;
                SLZ[c] += PERC;
                float Q2 = parK2[c] * SLZ[c];
                SLZ[c] -= Q2;

                q[c] = Q0 + Q1 + Q2;
            }
            const int t = t0 + j;
            if (t < NSTEP) {
                out[(size_t)t * NGRID + gi[0]] = q[0];
                out[(size_t)t * NGRID + gi[1]] = q[1];
            }
        }
    };

    // Software pipeline: double-buffered register prefetch, unrolled x2 so
    // both buffers are indexed with compile-time constants (stay in VGPRs).
    load_chunk(0, AP, AT, AE);
    int c = 0;
    for (;;) {
        if (c + 1 < nchunks) load_chunk(c + 1, BP, BT, BE);
        compute_chunk(c, AP, AT, AE);
        if (++c >= nchunks) break;
        if (c + 1 < nchunks) load_chunk(c + 1, AP, AT, AE);
        compute_chunk(c, BP, BT, BE);
        if (++c >= nchunks) break;
    }
}

extern "C" void kernel_launch(void* const* d_in, const int* in_sizes, int n_in,
                              void* d_out, int out_size, void* d_ws, size_t ws_size,
                              hipStream_t stream) {
    const float* x      = (const float*)d_in[0];
    const float* params = (const float*)d_in[1];
    float* out          = (float*)d_out;

    const int block = 64;
    const int grid  = (HALF + block - 1) / block;  // 391 waves, 2 cells/lane
    hbv_kernel<<<grid, block, 0, stream>>>(x, params, out);
}

// Round 3
// 333.724 us; speedup vs baseline: 1.0757x; 1.0757x over previous
//
#include <hip/hip_runtime.h>

#define NSTEP 365
#define NGRID 50000
#define PRECS_F 1e-5f
#define CHUNK 16
#define NCHUNKS ((NSTEP + CHUNK - 1) / CHUNK)   // 23
#define ROWDW   (NGRID * 3)                      // 150000 dwords per timestep row
#define XSIZE   (NSTEP * ROWDW)                  // total dwords in x
#define LOADS_PER_CHUNK 12                       // 16 rows * 192 dw / (64 lanes * 4 dw)

#if defined(__has_builtin)
#  if __has_builtin(__builtin_amdgcn_exp2f) && __has_builtin(__builtin_amdgcn_logf)
#    define FAST_EXP2(x) __builtin_amdgcn_exp2f(x)
#    define FAST_LOG2(x) __builtin_amdgcn_logf(x)
#  endif
#endif
#ifndef FAST_EXP2
#  define FAST_EXP2(x) exp2f(x)
#  define FAST_LOG2(x) log2f(x)
#endif

// Async global->LDS staging with the ONLY hardware-verified widths (4/16 B).
// Round-2 failed because size=12's per-lane LDS stride is not the documented
// lane*12 (only 4B/16B are measured in learn_hip m03/m97). Here each chunk
// (16 rows x 64 cells x 3 floats = 3072 dw) is staged as 12 flat 16B/lane
// DMA issues; since 192 dw/row % 4 == 0, each lane's 4-dword group sits
// entirely inside one row.
typedef __attribute__((address_space(3))) void lds_void_t;
typedef const __attribute__((address_space(1))) void glb_void_t;

__global__ __launch_bounds__(64) void hbv_kernel(const float* __restrict__ x,
                                                 const float* __restrict__ params,
                                                 float* __restrict__ out) {
    // 2 buffers x 3072 dwords = 24 KiB
    __shared__ float lds[2][CHUNK * 192];

    const int  lane  = threadIdx.x;
    const int  bid   = blockIdx.x;
    const int  gidx  = bid * 64 + lane;
    const int  g     = (gidx < NGRID) ? gidx : (NGRID - 1);  // clamp param reads
    const bool valid = (gidx < NGRID);

    // ---- scale parameters: p = lo + raw * (hi - lo) ----
    const float* pr = params + (size_t)g * 14;
    const float r0 = pr[0], r1 = pr[1], r2 = pr[2], r3 = pr[3], r4 = pr[4], r5 = pr[5];
    const float r6 = pr[6], r7 = pr[7], r8 = pr[8], r9 = pr[9], r10 = pr[10], r11 = pr[11];

    const float parBETA  = 1.0f   + r0  * 5.0f;
    const float parFC    = 50.0f  + r1  * 950.0f;
    const float parK0    = 0.05f  + r2  * 0.85f;
    const float parK1    = 0.01f  + r3  * 0.49f;
    const float parK2    = 0.001f + r4  * 0.199f;
    const float parLP    = 0.2f   + r5  * 0.8f;
    const float parPERC  =          r6  * 10.0f;
    const float parUZL   =          r7  * 100.0f;
    const float parTT    = -2.5f  + r8  * 5.0f;
    const float parCFMAX = 0.5f   + r9  * 9.5f;
    const float parCFR   =          r10 * 0.1f;
    const float parCWH   =          r11 * 0.2f;

    const float invFC     = 1.0f / parFC;
    const float invLPFC   = 1.0f / (parLP * parFC);
    const float cfr_cfmax = parCFR * parCFMAX;

    float SNOWPACK = 0.001f, MELTWATER = 0.001f, SM = 0.001f, SUZ = 0.001f, SLZ = 0.001f;

    // ---- async stage one chunk into an LDS buffer (12 x 16B/lane DMA) ----
    // flat dword f in chunk slab <-> row f/192, cell (f%192)/3, comp f%3.
    // Lane l of issue i writes dwords (i*64+l)*4 .. +3 (HW: base + lane*16).
    auto stage = [&](int buf, int cidx) {
        const int t0 = cidx * CHUNK;
        #pragma unroll
        for (int i = 0; i < LOADS_PER_CHUNK; ++i) {
            const int group = i * 64 + lane;   // 4-dword group index, 0..767
            const int r     = group / 48;      // row within chunk (192/4=48 groups/row)
            const int wg    = group % 48;      // group within row
            int t = t0 + r;
            t = (t < NSTEP) ? t : (NSTEP - 1);                 // tail-chunk clamp
            size_t off = (size_t)t * ROWDW + (size_t)bid * 192 + (size_t)(wg * 4);
            if (off > (size_t)(XSIZE - 4)) off = (size_t)(XSIZE - 4);  // last-block guard
            __builtin_amdgcn_global_load_lds((glb_void_t*)(x + off),
                                             (lds_void_t*)&lds[buf][i * 256],
                                             16, 0, 0);
        }
    };

    auto compute = [&](int buf, int cidx) {
        const int t0 = cidx * CHUNK;
        const float* __restrict__ L = &lds[buf][0];
        #pragma unroll
        for (int j = 0; j < CHUNK; ++j) {
            const float PRECIP = L[j * 192 + lane * 3 + 0];
            const float Tt     = L[j * 192 + lane * 3 + 1];
            const float ETp    = L[j * 192 + lane * 3 + 2];

            float RAIN = (Tt >= parTT) ? PRECIP : 0.0f;
            float SNOW = PRECIP - RAIN;
            SNOWPACK += SNOW;
            float melt = fminf(fmaxf(parCFMAX * (Tt - parTT), 0.0f), SNOWPACK);
            MELTWATER += melt;
            SNOWPACK  -= melt;
            float refreeze = fminf(fmaxf(cfr_cfmax * (parTT - Tt), 0.0f), MELTWATER);
            SNOWPACK  += refreeze;
            MELTWATER -= refreeze;
            float tosoil = fmaxf(MELTWATER - parCWH * SNOWPACK, 0.0f);
            MELTWATER -= tosoil;

            float ratio = SM * invFC;                     // SM in (0, FC] -> ratio in (0, 1]
            float sw = FAST_EXP2(parBETA * FAST_LOG2(ratio));
            sw = fminf(fmaxf(sw, 0.0f), 1.0f);
            float recharge = (RAIN + tosoil) * sw;
            SM += RAIN + tosoil - recharge;
            float excess = fmaxf(SM - parFC, 0.0f);
            SM -= excess;
            float evapfactor = fminf(fmaxf(SM * invLPFC, 0.0f), 1.0f);
            float ETact = fminf(SM, ETp * evapfactor);
            SM = fmaxf(SM - ETact, PRECS_F);

            SUZ += recharge + excess;
            float PERC = fminf(SUZ, parPERC);
            SUZ -= PERC;
            float Q0 = parK0 * fmaxf(SUZ - parUZL, 0.0f);
            SUZ -= Q0;
            float Q1 = parK1 * SUZ;
            SUZ -= Q1;
            SLZ += PERC;
            float Q2 = parK2 * SLZ;
            SLZ -= Q2;

            const int t = t0 + j;
            if (valid && (t < NSTEP)) out[(size_t)t * NGRID + gidx] = Q0 + Q1 + Q2;
        }
    };

    // ---- pipelined main loop (single wave per block: no barriers needed) ----
    stage(0, 0);
    for (int c = 0; c < NCHUNKS; ++c) {
        if (c + 1 < NCHUNKS) {
            stage((c + 1) & 1, c + 1);
            // Counted wait (T4): the 12 newest VM ops = next chunk's DMAs may
            // stay in flight; this chunk's DMAs + older stores must drain.
            asm volatile("s_waitcnt vmcnt(12)" ::: "memory");
        } else {
            asm volatile("s_waitcnt vmcnt(0)" ::: "memory");
        }
        __builtin_amdgcn_sched_barrier(0);   // keep ds_reads below the wait
        compute(c & 1, c);
    }
}

extern "C" void kernel_launch(void* const* d_in, const int* in_sizes, int n_in,
                              void* d_out, int out_size, void* d_ws, size_t ws_size,
                              hipStream_t stream) {
    const float* x      = (const float*)d_in[0];
    const float* params = (const float*)d_in[1];
    float* out          = (float*)d_out;

    const int block = 64;
    const int grid  = (NGRID + block - 1) / block;  // 782 waves, 1 cell/lane
    hbv_kernel<<<grid, block, 0, stream>>>(x, params, out);
}

// Round 4
// 331.851 us; speedup vs baseline: 1.0818x; 1.0056x over previous
//
#include <hip/hip_runtime.h>

#define NSTEP 365
#define NGRID 50000
#define PRECS_F 1e-5f
#define CHUNK 16
#define NCHUNKS ((NSTEP + CHUNK - 1) / CHUNK)   // 23 (22 full + tail of 13)
#define ROWDW   (NGRID * 3)                      // 150000 dwords per timestep row
#define XSIZE   (NSTEP * ROWDW)
#define LOADS_PER_CHUNK 12                       // 16 rows * 192 dw / (64 lanes * 4 dw)

#if defined(__has_builtin)
#  if __has_builtin(__builtin_amdgcn_exp2f) && __has_builtin(__builtin_amdgcn_logf)
#    define FAST_EXP2(x) __builtin_amdgcn_exp2f(x)
#    define FAST_LOG2(x) __builtin_amdgcn_logf(x)
#  endif
#endif
#ifndef FAST_EXP2
#  define FAST_EXP2(x) exp2f(x)
#  define FAST_LOG2(x) log2f(x)
#endif

typedef __attribute__((address_space(3))) void lds_void_t;
typedef const __attribute__((address_space(1))) void glb_void_t;

__global__ __launch_bounds__(64) void hbv_kernel(const float* __restrict__ x,
                                                 const float* __restrict__ params,
                                                 float* __restrict__ out) {
    // 2 buffers x 3072 dwords = 24 KiB
    __shared__ float lds[2][CHUNK * 192];

    const int  lane  = threadIdx.x;
    const int  bid   = blockIdx.x;
    const int  gidx  = bid * 64 + lane;
    const int  g     = (gidx < NGRID) ? gidx : (NGRID - 1);
    const bool valid = (gidx < NGRID);

    // ---- scale parameters: p = lo + raw * (hi - lo) ----
    const float* pr = params + (size_t)g * 14;
    const float r0 = pr[0], r1 = pr[1], r2 = pr[2], r3 = pr[3], r4 = pr[4], r5 = pr[5];
    const float r6 = pr[6], r7 = pr[7], r8 = pr[8], r9 = pr[9], r10 = pr[10], r11 = pr[11];

    const float parBETA  = 1.0f   + r0  * 5.0f;
    const float parFC    = 50.0f  + r1  * 950.0f;
    const float parK0    = 0.05f  + r2  * 0.85f;
    const float parK1    = 0.01f  + r3  * 0.49f;
    const float parK2    = 0.001f + r4  * 0.199f;
    const float parLP    = 0.2f   + r5  * 0.8f;
    const float parPERC  =          r6  * 10.0f;
    const float parUZL   =          r7  * 100.0f;
    const float parTT    = -2.5f  + r8  * 5.0f;
    const float parCFMAX = 0.5f   + r9  * 9.5f;
    const float parCFR   =          r10 * 0.1f;
    const float parCWH   =          r11 * 0.2f;

    const float invFC     = 1.0f / parFC;
    const float invLPFC   = 1.0f / (parLP * parFC);
    const float cfr_cfmax = parCFR * parCFMAX;

    float SNOWPACK = 0.001f, MELTWATER = 0.001f, SM = 0.001f, SUZ = 0.001f, SLZ = 0.001f;

    // ---- async stage one chunk (16 rows x 192 dw) as 12 x 16B/lane DMA ----
    auto stage = [&](int buf, int cidx) {
        const int t0 = cidx * CHUNK;
        #pragma unroll
        for (int i = 0; i < LOADS_PER_CHUNK; ++i) {
            const int group = i * 64 + lane;   // 4-dword group, 0..767
            const int r     = group / 48;      // row within chunk
            const int wg    = group % 48;      // group within row
            int t = t0 + r;
            t = (t < NSTEP) ? t : (NSTEP - 1);
            size_t off = (size_t)t * ROWDW + (size_t)bid * 192 + (size_t)(wg * 4);
            if (off > (size_t)(XSIZE - 4)) off = (size_t)(XSIZE - 4);
            __builtin_amdgcn_global_load_lds((glb_void_t*)(x + off),
                                             (lds_void_t*)&lds[buf][i * 256],
                                             16, 0, 0);
        }
    };

    // ---- consume one chunk: batched LDS->reg, then the pure-VALU chain ----
    auto compute = [&](int buf, int cidx) {
        const int t0 = cidx * CHUNK;
        const float* __restrict__ L = &lds[buf][0];

        // Batched readback: ONE lgkm drain per chunk instead of per step.
        float Pj[CHUNK], Tj[CHUNK], Ej[CHUNK];
        #pragma unroll
        for (int j = 0; j < CHUNK; ++j) {
            const int base = j * 192 + lane * 3;
            Pj[j] = L[base + 0];
            Tj[j] = L[base + 1];
            Ej[j] = L[base + 2];
        }

        float Qr[CHUNK];
        #pragma unroll
        for (int j = 0; j < CHUNK; ++j) {
            // input-only terms: state-independent, scheduler hoists off the chain
            const float RAIN    = (Tj[j] >= parTT) ? Pj[j] : 0.0f;
            const float SNOW    = Pj[j] - RAIN;
            const float meltcap = fmaxf(parCFMAX * (Tj[j] - parTT), 0.0f);
            const float refcap  = fmaxf(cfr_cfmax * (parTT - Tj[j]), 0.0f);

            SNOWPACK += SNOW;
            float melt = fminf(meltcap, SNOWPACK);
            MELTWATER += melt;
            SNOWPACK  -= melt;
            float refreeze = fminf(refcap, MELTWATER);
            SNOWPACK  += refreeze;
            MELTWATER -= refreeze;
            float tosoil = fmaxf(MELTWATER - parCWH * SNOWPACK, 0.0f);
            MELTWATER -= tosoil;

            float ratio = SM * invFC;                       // SM in (0, FC] -> (0,1]
            float sw = fminf(FAST_EXP2(parBETA * FAST_LOG2(ratio)), 1.0f); // >=0 free
            float inflow   = RAIN + tosoil;
            float recharge = inflow * sw;
            SM += inflow - recharge;
            float excess = fmaxf(SM - parFC, 0.0f);
            SM -= excess;
            float evapfactor = fminf(SM * invLPFC, 1.0f);   // >=0 free (SM>=PRECS)
            float ETact = fminf(SM, Ej[j] * evapfactor);
            SM = fmaxf(SM - ETact, PRECS_F);

            SUZ += recharge + excess;
            float PERC = fminf(SUZ, parPERC);
            SUZ -= PERC;
            float Q0 = parK0 * fmaxf(SUZ - parUZL, 0.0f);
            SUZ -= Q0;
            float Q1 = parK1 * SUZ;
            SUZ -= Q1;
            SLZ += PERC;
            float Q2 = parK2 * SLZ;
            SLZ -= Q2;

            Qr[j] = Q0 + Q1 + Q2;
        }

        // store batch: off the chain, fire-and-forget (exactly 16 issued for
        // c<=21 -> the vmcnt arithmetic below is static)
        #pragma unroll
        for (int j = 0; j < CHUNK; ++j) {
            const int t = t0 + j;
            if (valid && (t < NSTEP)) out[(size_t)t * NGRID + gidx] = Qr[j];
        }
    };

    // ---- pipelined main loop: counted waits that NEVER gate on stores ----
    // In-flight suffix at wait of iter c (issue order, oldest->newest):
    //   [L_c(12), S_{c-1}(16), L_{c+1}(12)]
    // vmcnt retires in order, so vmcnt(28) == "L_c done", stores untouched.
    stage(0, 0);
    stage(1, 1);
    asm volatile("s_waitcnt vmcnt(12)" ::: "memory");   // L_0 done; L_1 in flight
    __builtin_amdgcn_sched_barrier(0);
    compute(0, 0);
    for (int c = 1; c < NCHUNKS; ++c) {
        if (c + 1 < NCHUNKS) {
            stage((c + 1) & 1, c + 1);
            asm volatile("s_waitcnt vmcnt(28)" ::: "memory");  // L_c done; S_{c-1}+L_{c+1} free
        } else {
            asm volatile("s_waitcnt vmcnt(16)" ::: "memory");  // L_22 done; S_21 free
        }
        __builtin_amdgcn_sched_barrier(0);
        compute(c & 1, c);
    }
}

extern "C" void kernel_launch(void* const* d_in, const int* in_sizes, int n_in,
                              void* d_out, int out_size, void* d_ws, size_t ws_size,
                              hipStream_t stream) {
    const float* x      = (const float*)d_in[0];
    const float* params = (const float*)d_in[1];
    float* out          = (float*)d_out;

    const int block = 64;
    const int grid  = (NGRID + block - 1) / block;  // 782 waves, 1 cell/lane
    hbv_kernel<<<grid, block, 0, stream>>>(x, params, out);
}